// Round 4
// baseline (286.214 us; speedup 1.0000x reference)
//
#include <hip/hip_runtime.h>
#include <math.h>

// Problem constants (B=4, H=W=128, C=256, 2x2 pool, VALID)
#define HP   64
#define WPOL 64
#define C4   64                      // 256 channels / 4 (float4 groups)
#define NT4  (4 * HP * WPOL * C4)    // 1,048,576 float4 groups per output tensor
#define NELEM ((size_t)NT4 * 4)      // 4,194,304 floats per output tensor

typedef float vf4 __attribute__((ext_vector_type(4)));

// ---- float atomic min/max via int-representation monotone trick ----
__device__ __forceinline__ void atomicMaxF(float* addr, float val) {
    if (val >= 0.0f) atomicMax((int*)addr, __float_as_int(val));
    else             atomicMin((unsigned int*)addr, __float_as_uint(val));
}
__device__ __forceinline__ void atomicMinF(float* addr, float val) {
    if (val >= 0.0f) atomicMin((int*)addr, __float_as_int(val));
    else             atomicMax((unsigned int*)addr, __float_as_uint(val));
}

// Seed the two scalar outputs with l / u so the main kernel's atomics
// fold the final max(l, l_t) / min(u, u_t) clamp for free.
__global__ void init_kernel(const float* __restrict__ l_in,
                            const float* __restrict__ u_in,
                            float* __restrict__ out) {
    out[4 * NELEM]     = l_in[0];
    out[4 * NELEM + 1] = u_in[0];
}

// Hand-issued 16B load; result NOT valid until the explicit s_waitcnt below.
#define GLOAD(dst, ptr) \
    asm volatile("global_load_dwordx4 %0, %1, off" : "=v"(dst) : "v"(ptr))
#define GLOAD_OFS(dst, ptr) \
    asm volatile("global_load_dwordx4 %0, %1, off offset:1024" : "=v"(dst) : "v"(ptr))

__global__ __launch_bounds__(256) void maxpool_kernel(
    const vf4* __restrict__ x,  const vf4* __restrict__ bias,
    const vf4* __restrict__ a,  const vf4* __restrict__ bt,
    float* __restrict__ out)
{
    const int g  = blockIdx.x * 256 + threadIdx.x;   // [0, NT4)
    const int c4 = g & 63;
    const int wp = (g >> 6) & 63;
    const int hp = (g >> 12) & 63;
    const int bb = g >> 18;
    // input float4 index of window corner (ph=0, pw=0)
    const int base = ((bb * 128 + 2 * hp) * 128 + 2 * wp) * 64 + c4;

    // window order (ph,pw) = (0,0),(0,1),(1,0),(1,1) in float4 units:
    // +0, +64 (=+1024B, in-inst offset), +8192 (one h row = 128*64), +8256
    const vf4* px0 = x    + base;  const vf4* px1 = x    + base + 8192;
    const vf4* pb0 = bias + base;  const vf4* pb1 = bias + base + 8192;
    const vf4* pa0 = a    + base;  const vf4* pa1 = a    + base + 8192;
    const vf4* pc0 = bt   + base;  const vf4* pc1 = bt   + base + 8192;

    vf4 X0, X1, X2, X3, Bv0, Bv1, Bv2, Bv3, A0, A1, A2, A3, Bt0, Bt1, Bt2, Bt3;
    // 16 loads issued back-to-back: 16 KB outstanding per wave, ONE drain.
    GLOAD(X0,  px0);  GLOAD_OFS(X1,  px0);  GLOAD(X2,  px1);  GLOAD_OFS(X3,  px1);
    GLOAD(Bv0, pb0);  GLOAD_OFS(Bv1, pb0);  GLOAD(Bv2, pb1);  GLOAD_OFS(Bv3, pb1);
    GLOAD(A0,  pa0);  GLOAD_OFS(A1,  pa0);  GLOAD(A2,  pa1);  GLOAD_OFS(A3,  pa1);
    GLOAD(Bt0, pc0);  GLOAD_OFS(Bt1, pc0);  GLOAD(Bt2, pc1);  GLOAD_OFS(Bt3, pc1);
    // Single drain point; all 16 results pinned as in/outs so no consumer
    // can be hoisted above it and no load can sink below it.
    asm volatile("s_waitcnt vmcnt(0)"
                 : "+v"(X0),  "+v"(X1),  "+v"(X2),  "+v"(X3),
                   "+v"(Bv0), "+v"(Bv1), "+v"(Bv2), "+v"(Bv3),
                   "+v"(A0),  "+v"(A1),  "+v"(A2),  "+v"(A3),
                   "+v"(Bt0), "+v"(Bt1), "+v"(Bt2), "+v"(Bt3)
                 :: "memory");

    const vf4 X[4]  = {X0, X1, X2, X3};
    const vf4 Bv[4] = {Bv0, Bv1, Bv2, Bv3};
    const vf4 A[4]  = {A0, A1, A2, A3};
    const vf4 Bt[4] = {Bt0, Bt1, Bt2, Bt3};

    float lmax = -INFINITY, umin = INFINITY;
    vf4 rx, rb, ra, rc;

#pragma unroll
    for (int c = 0; c < 4; ++c) {
        float xw[4], bw[4], aw[4], cw[4];
#pragma unroll
        for (int j = 0; j < 4; ++j) {
            xw[j] = X[j][c];  bw[j] = Bv[j][c];
            aw[j] = A[j][c];  cw[j] = Bt[j][c];
        }
        // first-occurrence argmax (strict >) with fused gather of the other 3
        float sx = xw[0], sb = bw[0], sa = aw[0], sc = cw[0];
#pragma unroll
        for (int j = 1; j < 4; ++j) {
            bool gt = xw[j] > sx;
            sx = gt ? xw[j] : sx;
            sb = gt ? bw[j] : sb;
            sa = gt ? aw[j] : sa;
            sc = gt ? cw[j] : sc;
        }
        rx[c] = sx; rb[c] = sb; ra[c] = sa; rc[c] = sc;

        // truncated interval over the 4 window entries
#pragma unroll
        for (int j = 0; j < 4; ++j) {
            float tb  = cw[j] - sc;
            float nom = -((aw[j] - sa) + (bw[j] - sb));
            float q   = nom / tb;            // consumed only when tb != 0
            if (tb > 0.0f)      umin = fminf(umin, q);
            else if (tb < 0.0f) lmax = fmaxf(lmax, q);
        }
    }

    // coalesced float4 stores, outputs concatenated [x | bias | a | b | l | u]
    // issued BEFORE the reduction tail so store latency overlaps the shuffles
    ((vf4*)out)[g]               = rx;
    ((vf4*)(out + NELEM))[g]     = rb;
    ((vf4*)(out + 2 * NELEM))[g] = ra;
    ((vf4*)(out + 3 * NELEM))[g] = rc;

    // ---- block reduction of (lmax, umin) ----
#pragma unroll
    for (int s = 32; s; s >>= 1) {
        lmax = fmaxf(lmax, __shfl_down(lmax, s, 64));
        umin = fminf(umin, __shfl_down(umin, s, 64));
    }
    __shared__ float sl[4], su[4];
    const int wave = threadIdx.x >> 6;
    if ((threadIdx.x & 63) == 0) { sl[wave] = lmax; su[wave] = umin; }
    __syncthreads();
    if (threadIdx.x == 0) {
        float ll = fmaxf(fmaxf(sl[0], sl[1]), fmaxf(sl[2], sl[3]));
        float uu = fminf(fminf(su[0], su[1]), fminf(su[2], su[3]));
        atomicMaxF(&out[4 * NELEM],     ll);
        atomicMinF(&out[4 * NELEM + 1], uu);
    }
}

extern "C" void kernel_launch(void* const* d_in, const int* in_sizes, int n_in,
                              void* d_out, int out_size, void* d_ws, size_t ws_size,
                              hipStream_t stream) {
    const vf4* x    = (const vf4*)d_in[0];
    const vf4* bias = (const vf4*)d_in[1];
    const vf4* a    = (const vf4*)d_in[2];
    const vf4* bt   = (const vf4*)d_in[3];
    const float* l_in = (const float*)d_in[4];
    const float* u_in = (const float*)d_in[5];
    float* out = (float*)d_out;

    init_kernel<<<1, 1, 0, stream>>>(l_in, u_in, out);
    maxpool_kernel<<<NT4 / 256, 256, 0, stream>>>(x, bias, a, bt, out);
}

// Round 5
// 264.549 us; speedup vs baseline: 1.0819x; 1.0819x over previous
//
#include <hip/hip_runtime.h>
#include <math.h>

// Problem constants (B=4, H=W=128, C=256, 2x2 pool, VALID)
#define NT4   1048576                // float4 groups per output tensor
#define NELEM ((size_t)NT4 * 4)      // 4,194,304 floats per output tensor
#define GRID  512
#define ITERS 8                      // NT4 / (GRID*256)
#define STEP  (GRID * 256)           // 131072 tiles per grid pass

typedef float vf4 __attribute__((ext_vector_type(4)));

// ---- float atomic min/max via int-representation monotone trick ----
__device__ __forceinline__ void atomicMaxF(float* addr, float val) {
    if (val >= 0.0f) atomicMax((int*)addr, __float_as_int(val));
    else             atomicMin((unsigned int*)addr, __float_as_uint(val));
}
__device__ __forceinline__ void atomicMinF(float* addr, float val) {
    if (val >= 0.0f) atomicMin((int*)addr, __float_as_int(val));
    else             atomicMax((unsigned int*)addr, __float_as_uint(val));
}

__global__ void init_kernel(const float* __restrict__ l_in,
                            const float* __restrict__ u_in,
                            float* __restrict__ out) {
    out[4 * NELEM]     = l_in[0];
    out[4 * NELEM + 1] = u_in[0];
}

// Hand-issued 16B loads; results invalid until the matching waitcnt below.
#define GLOAD(dst, ptr) \
    asm volatile("global_load_dwordx4 %0, %1, off" : "=v"(dst) : "v"(ptr))
#define GLOAD_OFS(dst, ptr) \
    asm volatile("global_load_dwordx4 %0, %1, off offset:1024" : "=v"(dst) : "v"(ptr))

// input float4 index of window corner (ph=0, pw=0) for tile gi
__device__ __forceinline__ int baseof(int gi) {
    return (((gi >> 18) * 128 + 2 * ((gi >> 12) & 63)) * 128
            + 2 * ((gi >> 6) & 63)) * 64 + (gi & 63);
}

// issue 16 loads (one tile, 4 tensors x 4 window slots), no wait
#define LOAD_SET(X, Bv, A, Ct, gi) do {                                     \
    const int base_ = baseof(gi);                                           \
    const vf4* px_ = x    + base_;  const vf4* pb_ = bias + base_;          \
    const vf4* pa_ = a    + base_;  const vf4* pc_ = bt   + base_;          \
    GLOAD(X[0],  px_); GLOAD_OFS(X[1],  px_);                               \
    GLOAD(X[2],  px_ + 8192); GLOAD_OFS(X[3],  px_ + 8192);                 \
    GLOAD(Bv[0], pb_); GLOAD_OFS(Bv[1], pb_);                               \
    GLOAD(Bv[2], pb_ + 8192); GLOAD_OFS(Bv[3], pb_ + 8192);                 \
    GLOAD(A[0],  pa_); GLOAD_OFS(A[1],  pa_);                               \
    GLOAD(A[2],  pa_ + 8192); GLOAD_OFS(A[3],  pa_ + 8192);                 \
    GLOAD(Ct[0], pc_); GLOAD_OFS(Ct[1], pc_);                               \
    GLOAD(Ct[2], pc_ + 8192); GLOAD_OFS(Ct[3], pc_ + 8192);                 \
} while (0)

// wait until only the N newest vmem ops remain outstanding; pins this set's
// 16 results so consumers can't hoist above and the loads can't sink below
#define WAIT_SET(N, X, Bv, A, Ct)                                           \
    asm volatile("s_waitcnt vmcnt(" #N ")"                                  \
                 : "+v"(X[0]),  "+v"(X[1]),  "+v"(X[2]),  "+v"(X[3]),       \
                   "+v"(Bv[0]), "+v"(Bv[1]), "+v"(Bv[2]), "+v"(Bv[3]),      \
                   "+v"(A[0]),  "+v"(A[1]),  "+v"(A[2]),  "+v"(A[3]),       \
                   "+v"(Ct[0]), "+v"(Ct[1]), "+v"(Ct[2]), "+v"(Ct[3])       \
                 :: "memory")

__device__ __forceinline__ void process_tile(
    const vf4 (&X)[4], const vf4 (&Bv)[4], const vf4 (&A)[4], const vf4 (&Ct)[4],
    int gi, float* __restrict__ out, float& lmax, float& umin)
{
    vf4 rx, rb, ra, rc;
#pragma unroll
    for (int c = 0; c < 4; ++c) {
        float xw[4], bw[4], aw[4], cw[4];
#pragma unroll
        for (int j = 0; j < 4; ++j) {
            xw[j] = X[j][c];  bw[j] = Bv[j][c];
            aw[j] = A[j][c];  cw[j] = Ct[j][c];
        }
        // first-occurrence argmax (strict >) with fused gather of the other 3
        float sx = xw[0], sb = bw[0], sa = aw[0], sc = cw[0];
#pragma unroll
        for (int j = 1; j < 4; ++j) {
            bool gt = xw[j] > sx;
            sx = gt ? xw[j] : sx;
            sb = gt ? bw[j] : sb;
            sa = gt ? aw[j] : sa;
            sc = gt ? cw[j] : sc;
        }
        rx[c] = sx; rb[c] = sb; ra[c] = sa; rc[c] = sc;
        // truncated interval over the 4 window entries
#pragma unroll
        for (int j = 0; j < 4; ++j) {
            float tb  = cw[j] - sc;
            float nom = -((aw[j] - sa) + (bw[j] - sb));
            float q   = nom / tb;            // consumed only when tb != 0
            if (tb > 0.0f)      umin = fminf(umin, q);
            else if (tb < 0.0f) lmax = fmaxf(lmax, q);
        }
    }
    ((vf4*)out)[gi]               = rx;
    ((vf4*)(out + NELEM))[gi]     = rb;
    ((vf4*)(out + 2 * NELEM))[gi] = ra;
    ((vf4*)(out + 3 * NELEM))[gi] = rc;
}

__global__ __launch_bounds__(256) void maxpool_kernel(
    const vf4* __restrict__ x,  const vf4* __restrict__ bias,
    const vf4* __restrict__ a,  const vf4* __restrict__ bt,
    float* __restrict__ out)
{
    const int g = blockIdx.x * 256 + threadIdx.x;   // first tile of this thread

    vf4 XA[4], BA[4], AA[4], CA[4];
    vf4 XB[4], BB[4], AB[4], CB[4];
    float lmax = -INFINITY, umin = INFINITY;

    // persistent double-buffered stream: the 16 newest loads are ALWAYS in
    // flight while the previous tile computes (vmcnt(16) = drain older only)
    LOAD_SET(XA, BA, AA, CA, g);
#pragma unroll
    for (int it = 0; it < ITERS; it += 2) {
        const int gA = g + it * STEP, gB = gA + STEP, gC = gA + 2 * STEP;
        LOAD_SET(XB, BB, AB, CB, gB);
        WAIT_SET(16, XA, BA, AA, CA);
        process_tile(XA, BA, AA, CA, gA, out, lmax, umin);
        if (it + 2 < ITERS) {
            LOAD_SET(XA, BA, AA, CA, gC);
            WAIT_SET(16, XB, BB, AB, CB);
        } else {
            WAIT_SET(0, XB, BB, AB, CB);
        }
        process_tile(XB, BB, AB, CB, gB, out, lmax, umin);
    }

    // ---- block reduction of (lmax, umin), once per block ----
#pragma unroll
    for (int s = 32; s; s >>= 1) {
        lmax = fmaxf(lmax, __shfl_down(lmax, s, 64));
        umin = fminf(umin, __shfl_down(umin, s, 64));
    }
    __shared__ float sl[4], su[4];
    const int wave = threadIdx.x >> 6;
    if ((threadIdx.x & 63) == 0) { sl[wave] = lmax; su[wave] = umin; }
    __syncthreads();
    if (threadIdx.x == 0) {
        float ll = fmaxf(fmaxf(sl[0], sl[1]), fmaxf(sl[2], sl[3]));
        float uu = fminf(fminf(su[0], su[1]), fminf(su[2], su[3]));
        atomicMaxF(&out[4 * NELEM],     ll);
        atomicMinF(&out[4 * NELEM + 1], uu);
    }
}

extern "C" void kernel_launch(void* const* d_in, const int* in_sizes, int n_in,
                              void* d_out, int out_size, void* d_ws, size_t ws_size,
                              hipStream_t stream) {
    const vf4* x    = (const vf4*)d_in[0];
    const vf4* bias = (const vf4*)d_in[1];
    const vf4* a    = (const vf4*)d_in[2];
    const vf4* bt   = (const vf4*)d_in[3];
    const float* l_in = (const float*)d_in[4];
    const float* u_in = (const float*)d_in[5];
    float* out = (float*)d_out;

    init_kernel<<<1, 1, 0, stream>>>(l_in, u_in, out);
    maxpool_kernel<<<GRID, 256, 0, stream>>>(x, bias, a, bt, out);
}